// Round 1
// baseline (268.682 us; speedup 1.0000x reference)
//
#include <hip/hip_runtime.h>

#define N_SEQ 2048
#define CDIM 512
#define HEADS 8
#define DH 64
#define WINDOW 64
#define BATCH 2

// ---------- helpers ----------
__device__ __forceinline__ float bflo(unsigned u){ return __uint_as_float(u << 16); }
__device__ __forceinline__ float bfhi(unsigned u){ return __uint_as_float(u & 0xffff0000u); }
__device__ __forceinline__ unsigned short f2b(float f){
  unsigned u = __float_as_uint(f);
  unsigned r = (u + 0x7fffu + ((u >> 16) & 1u)) >> 16;
  return (unsigned short)r;
}
__device__ __forceinline__ float b2f(unsigned short h){ return __uint_as_float(((unsigned)h) << 16); }

__device__ __forceinline__ float dot8(uint4 a, uint4 b){
  return bflo(a.x)*bflo(b.x) + bfhi(a.x)*bfhi(b.x)
       + bflo(a.y)*bflo(b.y) + bfhi(a.y)*bfhi(b.y)
       + bflo(a.z)*bflo(b.z) + bfhi(a.z)*bfhi(b.z)
       + bflo(a.w)*bflo(b.w) + bfhi(a.w)*bfhi(b.w);
}

__device__ __forceinline__ float wave_max(float v){
  #pragma unroll
  for (int off = 32; off; off >>= 1) v = fmaxf(v, __shfl_xor(v, off));
  return v;
}
__device__ __forceinline__ float wave_sum(float v){
  #pragma unroll
  for (int off = 32; off; off >>= 1) v += __shfl_xor(v, off);
  return v;
}

// ---------- kernel 1/4: rank-8 projection  out[m][r] = sum_c in[m][c]*A[c][r] ----------
__global__ __launch_bounds__(256) void rank8_kernel(const float* __restrict__ in,
    const float* __restrict__ A, float* __restrict__ outp){
  const int w = threadIdx.x >> 6, lane = threadIdx.x & 63;
  const int m = blockIdx.x * 4 + w;
  float acc[8] = {0.f,0.f,0.f,0.f,0.f,0.f,0.f,0.f};
  const float* row = in + (size_t)m * CDIM;
  #pragma unroll
  for (int c0 = 0; c0 < 8; c0++){
    int c = c0*64 + lane;
    float xv = row[c];
    const float4* ap = (const float4*)(A + (size_t)c*8);
    float4 a0 = ap[0], a1 = ap[1];
    acc[0] += xv*a0.x; acc[1] += xv*a0.y; acc[2] += xv*a0.z; acc[3] += xv*a0.w;
    acc[4] += xv*a1.x; acc[5] += xv*a1.y; acc[6] += xv*a1.z; acc[7] += xv*a1.w;
  }
  #pragma unroll
  for (int r = 0; r < 8; r++) acc[r] = wave_sum(acc[r]);
  if (lane == 0){
    #pragma unroll
    for (int r = 0; r < 8; r++) outp[(size_t)m*8 + r] = acc[r];
  }
}

// ---------- kernel 2: qkv = x@w_qkv + 0.25*xa@lB, scattered to q/k/v (b,h,n,d) ----------
__global__ __launch_bounds__(256) void qkv_gemm(const float* __restrict__ x,
    const float* __restrict__ w, const float* __restrict__ xa,
    const float* __restrict__ lB, float* __restrict__ qbase){
  __shared__ float As[16][68];
  __shared__ float Bs[16][68];
  const int ct = blockIdx.x, rt = blockIdx.y;
  const int tid = threadIdx.x, tx = tid & 15, ty = tid >> 4;
  const int m0 = rt*64, n0 = ct*64;
  float acc[4][4] = {};
  for (int kk = 0; kk < 512; kk += 16){
    int ac = tid & 15, ar = tid >> 4;
    #pragma unroll
    for (int i = 0; i < 4; i++)
      As[ac][ar + 16*i] = x[(size_t)(m0 + ar + 16*i)*512 + kk + ac];
    int bn = tid & 63, bk = tid >> 6;
    #pragma unroll
    for (int i = 0; i < 4; i++)
      Bs[bk + 4*i][bn] = w[(size_t)(kk + bk + 4*i)*1536 + n0 + bn];
    __syncthreads();
    #pragma unroll
    for (int kq = 0; kq < 16; kq++){
      const float4 a4 = *(const float4*)&As[kq][ty*4];
      const float4 b4 = *(const float4*)&Bs[kq][tx*4];
      float av[4] = {a4.x,a4.y,a4.z,a4.w};
      float bv[4] = {b4.x,b4.y,b4.z,b4.w};
      #pragma unroll
      for (int ii = 0; ii < 4; ii++)
        #pragma unroll
        for (int jj = 0; jj < 4; jj++)
          acc[ii][jj] += av[ii]*bv[jj];
    }
    __syncthreads();
  }
  const int t = ct >> 3, h = ct & 7;
  float* dst = qbase + (size_t)t * ((size_t)BATCH*HEADS*N_SEQ*DH);
  #pragma unroll
  for (int i = 0; i < 4; i++){
    int m = m0 + ty*4 + i;
    int b = m >> 11, n = m & 2047;
    float xa8[8];
    #pragma unroll
    for (int r = 0; r < 8; r++) xa8[r] = xa[(size_t)m*8 + r];
    float* drow = dst + ((size_t)(b*HEADS + h)*N_SEQ + n)*DH;
    #pragma unroll
    for (int j = 0; j < 4; j++){
      int d = tx*4 + j;
      int jg = n0 + d;
      float lo = 0.f;
      #pragma unroll
      for (int r = 0; r < 8; r++) lo += xa8[r]*lB[(size_t)r*1536 + jg];
      drow[d] = acc[i][j] + 0.25f*lo;
    }
  }
}

// ---------- kernel 3: fused local(banded causal) + global(strided) attention ----------
__global__ __launch_bounds__(256) void attn_kernel(const float* __restrict__ q,
    const float* __restrict__ k, const float* __restrict__ v, float* __restrict__ o){
  __shared__ __align__(16) unsigned short Qt[64][72];
  __shared__ __align__(16) unsigned short Kt[128][72];
  __shared__ __align__(16) unsigned short Vt[128][72];
  __shared__ __align__(16) unsigned short Kg[32][72];
  __shared__ __align__(16) unsigned short Vg[32][72];
  const int qt = blockIdx.x, bh = blockIdx.y;
  const int qbase = qt * 64;
  const int tid = threadIdx.x;
  const float* qp = q + (size_t)bh * N_SEQ * DH;
  const float* kp = k + (size_t)bh * N_SEQ * DH;
  const float* vp = v + (size_t)bh * N_SEQ * DH;
  for (int idx = tid; idx < 64*64; idx += 256){
    int r = idx >> 6, d = idx & 63;
    Qt[r][d] = f2b(qp[(size_t)(qbase + r)*DH + d]);
  }
  for (int idx = tid; idx < 128*64; idx += 256){
    int r = idx >> 6, d = idx & 63;
    int row = qbase - 64 + r;
    Kt[r][d] = (row >= 0) ? f2b(kp[(size_t)row*DH + d]) : (unsigned short)0;
    Vt[r][d] = (row >= 0) ? f2b(vp[(size_t)row*DH + d]) : (unsigned short)0;
  }
  for (int idx = tid; idx < 32*64; idx += 256){
    int r = idx >> 6, d = idx & 63;
    Kg[r][d] = f2b(kp[(size_t)r*WINDOW*DH + d]);
    Vg[r][d] = f2b(vp[(size_t)r*WINDOW*DH + d]);
  }
  __syncthreads();
  const int w = tid >> 6, lane = tid & 63;
  const int b = bh >> 3, h = bh & 7;
  for (int rr = 0; rr < 16; rr++){
    const int i_loc = w*16 + rr;
    const int i = qbase + i_loc;
    const uint4* qrow = (const uint4*)&Qt[i_loc][0];
    const uint4* k0 = (const uint4*)&Kt[lane][0];
    const uint4* k1 = (const uint4*)&Kt[64+lane][0];
    float s0 = 0.f, s1 = 0.f;
    #pragma unroll
    for (int c = 0; c < 8; c++){
      uint4 qc = qrow[c];
      s0 += dot8(qc, k0[c]);
      s1 += dot8(qc, k1[c]);
    }
    s0 *= 0.125f; s1 *= 0.125f;
    const bool v0 = (qt > 0) && (lane >= i_loc);   // key j = qbase-64+lane
    const bool v1 = (lane <= i_loc);               // key j = qbase+lane
    float m = fmaxf(v0 ? s0 : -1e30f, v1 ? s1 : -1e30f);
    m = wave_max(m);
    float p0 = v0 ? __expf(s0 - m) : 0.f;
    float p1 = v1 ? __expf(s1 - m) : 0.f;
    float inv = 1.f / wave_sum(p0 + p1);
    float p0n = p0 * inv, p1n = p1 * inv;
    float accl = 0.f;
    #pragma unroll 4
    for (int r2 = 0; r2 < 64; r2++){
      float pa = __shfl(p0n, r2);
      float pb = __shfl(p1n, r2);
      accl += pa * b2f(Vt[r2][lane]) + pb * b2f(Vt[64+r2][lane]);
    }
    // global (strided) attention: 32 keys, no mask
    const uint4* kg = (const uint4*)&Kg[lane & 31][0];
    float sg = 0.f;
    #pragma unroll
    for (int c = 0; c < 8; c++) sg += dot8(qrow[c], kg[c]);
    sg *= 0.125f;
    const bool vgd = lane < 32;
    float mg = wave_max(vgd ? sg : -1e30f);
    float pg = vgd ? __expf(sg - mg) : 0.f;
    float pgn = pg / wave_sum(pg);
    float accg = 0.f;
    #pragma unroll 4
    for (int r2 = 0; r2 < 32; r2++) accg += __shfl(pgn, r2) * b2f(Vg[r2][lane]);
    o[((size_t)(b*N_SEQ + i))*CDIM + h*DH + lane] = accl + accg;
  }
}

// ---------- kernel 5: out = attn@w_out + b_out + 0.25*ao@lB_out ----------
__global__ __launch_bounds__(256) void out_gemm(const float* __restrict__ a,
    const float* __restrict__ w, const float* __restrict__ ao,
    const float* __restrict__ lB, const float* __restrict__ bias, float* __restrict__ outp){
  __shared__ float As[16][68];
  __shared__ float Bs[16][68];
  const int ct = blockIdx.x, rt = blockIdx.y;
  const int tid = threadIdx.x, tx = tid & 15, ty = tid >> 4;
  const int m0 = rt*64, n0 = ct*64;
  float acc[4][4] = {};
  for (int kk = 0; kk < 512; kk += 16){
    int ac = tid & 15, ar = tid >> 4;
    #pragma unroll
    for (int i = 0; i < 4; i++)
      As[ac][ar + 16*i] = a[(size_t)(m0 + ar + 16*i)*512 + kk + ac];
    int bn = tid & 63, bk = tid >> 6;
    #pragma unroll
    for (int i = 0; i < 4; i++)
      Bs[bk + 4*i][bn] = w[(size_t)(kk + bk + 4*i)*512 + n0 + bn];
    __syncthreads();
    #pragma unroll
    for (int kq = 0; kq < 16; kq++){
      const float4 a4 = *(const float4*)&As[kq][ty*4];
      const float4 b4 = *(const float4*)&Bs[kq][tx*4];
      float av[4] = {a4.x,a4.y,a4.z,a4.w};
      float bv[4] = {b4.x,b4.y,b4.z,b4.w};
      #pragma unroll
      for (int ii = 0; ii < 4; ii++)
        #pragma unroll
        for (int jj = 0; jj < 4; jj++)
          acc[ii][jj] += av[ii]*bv[jj];
    }
    __syncthreads();
  }
  #pragma unroll
  for (int i = 0; i < 4; i++){
    int m = m0 + ty*4 + i;
    float ao8[8];
    #pragma unroll
    for (int r = 0; r < 8; r++) ao8[r] = ao[(size_t)m*8 + r];
    #pragma unroll
    for (int j = 0; j < 4; j++){
      int jg = n0 + tx*4 + j;
      float lo = 0.f;
      #pragma unroll
      for (int r = 0; r < 8; r++) lo += ao8[r]*lB[(size_t)r*512 + jg];
      outp[(size_t)m*512 + jg] = acc[i][j] + bias[jg] + 0.25f*lo;
    }
  }
}

extern "C" void kernel_launch(void* const* d_in, const int* in_sizes, int n_in,
                              void* d_out, int out_size, void* d_ws, size_t ws_size,
                              hipStream_t stream){
  const float* x      = (const float*)d_in[0];
  const float* w_qkv  = (const float*)d_in[1];
  const float* lA_qkv = (const float*)d_in[2];
  const float* lB_qkv = (const float*)d_in[3];
  const float* w_out  = (const float*)d_in[4];
  const float* b_out  = (const float*)d_in[5];
  const float* lA_out = (const float*)d_in[6];
  const float* lB_out = (const float*)d_in[7];
  float* out = (float*)d_out;
  float* ws  = (float*)d_ws;

  const size_t QKVSZ = (size_t)BATCH*HEADS*N_SEQ*DH;   // 2,097,152 floats
  float* q    = ws;
  float* kbuf = ws + QKVSZ;
  float* vbuf = ws + 2*QKVSZ;
  float* attn = ws + 3*QKVSZ;                          // 4096x512
  float* xa   = ws + 3*QKVSZ + (size_t)4096*512;       // 4096x8
  float* ao   = xa + (size_t)4096*8;                   // 4096x8

  rank8_kernel<<<1024, 256, 0, stream>>>(x, lA_qkv, xa);
  qkv_gemm<<<dim3(24, 64), 256, 0, stream>>>(x, w_qkv, xa, lB_qkv, q);
  attn_kernel<<<dim3(32, 16), 256, 0, stream>>>(q, kbuf, vbuf, attn);
  rank8_kernel<<<1024, 256, 0, stream>>>(attn, lA_out, ao);
  out_gemm<<<dim3(8, 64), 256, 0, stream>>>(attn, w_out, ao, lB_out, b_out, out);
}

// Round 2
// 73.234 us; speedup vs baseline: 3.6688x; 3.6688x over previous
//
#include <hip/hip_runtime.h>

#define N_SEQ 2048
#define CDIM 512
#define HEADS 8
#define DH 64
#define WINDOW 64
#define BATCH 2
#define KP 544           // 512 + 8 lora + 24 zero pad (17 * 32)

typedef __attribute__((ext_vector_type(8))) short bf16x8;
typedef __attribute__((ext_vector_type(4))) short short4v;
typedef __attribute__((ext_vector_type(8))) short short8v;
typedef __attribute__((ext_vector_type(4))) float f32x4;

// ---------- helpers ----------
__device__ __forceinline__ unsigned short f2b(float f){
  unsigned u = __float_as_uint(f);
  unsigned r = (u + 0x7fffu + ((u >> 16) & 1u)) >> 16;
  return (unsigned short)r;
}
__device__ __forceinline__ float b2f(unsigned short h){ return __uint_as_float(((unsigned)h) << 16); }

__device__ __forceinline__ void gl_lds16(const void* g, void* l){
  __builtin_amdgcn_global_load_lds(
      (const __attribute__((address_space(1))) void*)g,
      (__attribute__((address_space(3))) void*)l, 16, 0, 0);
}

__device__ __forceinline__ float wave_sum(float v){
  #pragma unroll
  for (int off = 32; off; off >>= 1) v += __shfl_xor(v, off);
  return v;
}

// ---------- cvt x (f32 [4096][512]) -> A1 bf16 [4096][KP] cols 0..511 ----------
__global__ __launch_bounds__(256) void cvt_x(const float* __restrict__ x, short* __restrict__ A1){
  int idx = blockIdx.x * 256 + threadIdx.x;      // one float4 each; 4096*128 total
  int m = idx >> 7, c4 = idx & 127;
  float4 v = ((const float4*)x)[(size_t)m*128 + c4];
  short4v pk;
  pk[0] = (short)f2b(v.x); pk[1] = (short)f2b(v.y);
  pk[2] = (short)f2b(v.z); pk[3] = (short)f2b(v.w);
  *(short4v*)&A1[(size_t)m*KP + c4*4] = pk;
}

// ---------- rank8: dst[m][512+r] = sum_c in[m][c]*Amat[c][r]; cols 520..543 = 0 ----------
template<bool BF16IN>
__global__ __launch_bounds__(256) void rank8_k(const void* __restrict__ inp,
    const float* __restrict__ Amat, short* __restrict__ dst){
  const int w = threadIdx.x >> 6, lane = threadIdx.x & 63;
  const int m = blockIdx.x * 4 + w;
  float acc[8] = {0.f,0.f,0.f,0.f,0.f,0.f,0.f,0.f};
  #pragma unroll
  for (int c0 = 0; c0 < 8; c0++){
    int c = c0*64 + lane;
    float xv;
    if (BF16IN) xv = b2f(((const unsigned short*)inp)[(size_t)m*KP + c]);
    else        xv = ((const float*)inp)[(size_t)m*CDIM + c];
    const float4* ap = (const float4*)(Amat + (size_t)c*8);
    float4 a0 = ap[0], a1 = ap[1];
    acc[0] += xv*a0.x; acc[1] += xv*a0.y; acc[2] += xv*a0.z; acc[3] += xv*a0.w;
    acc[4] += xv*a1.x; acc[5] += xv*a1.y; acc[6] += xv*a1.z; acc[7] += xv*a1.w;
  }
  #pragma unroll
  for (int r = 0; r < 8; r++) acc[r] = wave_sum(acc[r]);
  float myv = 0.f;
  #pragma unroll
  for (int r = 0; r < 8; r++) if (lane == r) myv = acc[r];
  if (lane < 32) dst[(size_t)m*KP + 512 + lane] = (lane < 8) ? (short)f2b(myv) : (short)0;
}

// ---------- build wT: w [512][NN] f32 (+ lB [8][NN]*scale) -> wT bf16 [NN][KP] ----------
template<int NN>
__global__ __launch_bounds__(256) void build_wT(const float* __restrict__ w,
    const float* __restrict__ lB, float scale, short* __restrict__ wT){
  const int tid = threadIdx.x;
  const int n0 = blockIdx.x * 64;
  const int by = blockIdx.y;
  if (by == 8){
    int nl = tid & 63, quarter = tid >> 6;
    int n = n0 + nl;
    short8v pk;
    #pragma unroll
    for (int i = 0; i < 8; i++){
      int j = quarter*8 + i;
      pk[i] = (j < 8) ? (short)f2b(scale * lB[(size_t)j*NN + n]) : (short)0;
    }
    *(short8v*)&wT[(size_t)n*KP + 512 + quarter*8] = pk;
    return;
  }
  __shared__ float T[64][65];
  const int k0 = by * 64;
  #pragma unroll
  for (int it = 0; it < 16; it++){
    int r = (tid >> 6) + it*4, c = tid & 63;
    T[r][c] = w[(size_t)(k0 + r)*NN + n0 + c];
  }
  __syncthreads();
  #pragma unroll
  for (int it = 0; it < 16; it++){
    int rw = (tid >> 6) + it*4, cw = tid & 63;
    wT[(size_t)(n0 + rw)*KP + k0 + cw] = (short)f2b(T[cw][rw]);
  }
}

// ---------- MFMA GEMM: C[m][n] = sum_k A[m][k]*Bt[n][k]; EPI 0 = qkv scatter, 1 = out ----------
template<int BM, int BN, int FM, int FN, int EPI>
__global__ __launch_bounds__(256) void gemm_mfma(const short* __restrict__ A,
    const short* __restrict__ Bt,
    short* __restrict__ qb, short* __restrict__ kb,
    short* __restrict__ vT, short* __restrict__ vgT,
    const float* __restrict__ bias, float* __restrict__ outp){
  __shared__ __align__(16) short As[BM*32];
  __shared__ __align__(16) short Bs[BN*32];
  const int tid = threadIdx.x;
  const int wid = tid >> 6, lane = tid & 63;
  const int ln = lane & 15, lg = lane >> 4;
  constexpr int NWC = BN / (16*FN);
  const int wr = wid / NWC, wc = wid % NWC;
  const int m0 = blockIdx.y * BM, n0 = blockIdx.x * BN;
  f32x4 acc[FM][FN];
  #pragma unroll
  for (int mi = 0; mi < FM; mi++)
    #pragma unroll
    for (int ni = 0; ni < FN; ni++){ f32x4 z = {0.f,0.f,0.f,0.f}; acc[mi][ni] = z; }

  for (int kt = 0; kt < KP/32; kt++){
    const int k0 = kt*32;
    if (kt) __syncthreads();
    #pragma unroll
    for (int i = 0; i < BM/64; i++){
      int li = i*256 + tid;
      int row = li >> 2, p = li & 3;
      int sl = p ^ ((row >> 1) & 3);
      gl_lds16(&A[(size_t)(m0 + row)*KP + k0 + sl*8], &As[(i*256 + wid*64)*8]);
    }
    #pragma unroll
    for (int i = 0; i < BN/64; i++){
      int li = i*256 + tid;
      int row = li >> 2, p = li & 3;
      int sl = p ^ ((row >> 1) & 3);
      gl_lds16(&Bt[(size_t)(n0 + row)*KP + k0 + sl*8], &Bs[(i*256 + wid*64)*8]);
    }
    asm volatile("s_waitcnt vmcnt(0)" ::: "memory");
    __syncthreads();
    bf16x8 af[FM], bfr[FN];
    #pragma unroll
    for (int mi = 0; mi < FM; mi++){
      int row = wr*FM*16 + mi*16 + ln;
      af[mi] = *(const bf16x8*)&As[row*32 + ((lg ^ ((row >> 1) & 3)) << 3)];
    }
    #pragma unroll
    for (int ni = 0; ni < FN; ni++){
      int row = wc*FN*16 + ni*16 + ln;
      bfr[ni] = *(const bf16x8*)&Bs[row*32 + ((lg ^ ((row >> 1) & 3)) << 3)];
    }
    #pragma unroll
    for (int mi = 0; mi < FM; mi++)
      #pragma unroll
      for (int ni = 0; ni < FN; ni++)
        acc[mi][ni] = __builtin_amdgcn_mfma_f32_16x16x32_bf16(af[mi], bfr[ni], acc[mi][ni], 0, 0, 0);
  }

  if constexpr (EPI == 0){
    #pragma unroll
    for (int mi = 0; mi < FM; mi++){
      int mbase = m0 + wr*FM*16 + mi*16 + lg*4;
      int b = mbase >> 11, nseq = mbase & 2047;
      #pragma unroll
      for (int ni = 0; ni < FN; ni++){
        int jg = n0 + wc*FN*16 + ni*16 + ln;
        int s = jg >> 9, rem = jg & 511;
        int h = rem >> 6, d = rem & 63;
        size_t bh = (size_t)(b*HEADS + h);
        f32x4 a = acc[mi][ni];
        if (s == 2){
          short4v pk;
          pk[0] = (short)f2b(a[0]); pk[1] = (short)f2b(a[1]);
          pk[2] = (short)f2b(a[2]); pk[3] = (short)f2b(a[3]);
          *(short4v*)&vT[bh*131072 + (size_t)d*2048 + nseq] = pk;
          if ((nseq & 63) == 0) vgT[bh*2048 + d*32 + (nseq >> 6)] = pk[0];
        } else {
          short* dst = (s == 0 ? qb : kb) + bh*131072 + (size_t)nseq*64 + d;
          dst[0]   = (short)f2b(a[0]);
          dst[64]  = (short)f2b(a[1]);
          dst[128] = (short)f2b(a[2]);
          dst[192] = (short)f2b(a[3]);
        }
      }
    }
  } else {
    #pragma unroll
    for (int mi = 0; mi < FM; mi++){
      int mbase = m0 + wr*FM*16 + mi*16 + lg*4;
      #pragma unroll
      for (int ni = 0; ni < FN; ni++){
        int jg = n0 + wc*FN*16 + ni*16 + ln;
        float bi = bias[jg];
        #pragma unroll
        for (int r = 0; r < 4; r++)
          outp[(size_t)(mbase + r)*CDIM + jg] = acc[mi][ni][r] + bi;
      }
    }
  }
}

// ---------- fused attention (MFMA): S^T = mfma(K,Q); softmax in-reg; PV over [local|global] ----------
__global__ __launch_bounds__(256) void attn_mfma(const short* __restrict__ qb,
    const short* __restrict__ kb, const short* __restrict__ vT,
    const short* __restrict__ vgT, short* __restrict__ A2){
  __shared__ __align__(16) short Ps[4][16][168];
  const int qt = blockIdx.x, bh = blockIdx.y;
  const int qbase = qt * 64;
  const int tid = threadIdx.x, w = tid >> 6, lane = tid & 63;
  const int ln = lane & 15, lg = lane >> 4;
  const size_t base = (size_t)bh * (N_SEQ * DH);
  const short* Qp = qb + base;
  const short* Kp = kb + base;
  const short* Vt = vT + base;
  const short* Vg = vgT + (size_t)bh * (DH * 32);
  const int i = qbase + w*16 + ln;          // this lane's query index
  const int kwin0 = qbase - 64;

  // Q B-fragments (natural layout: row i, contiguous d)
  bf16x8 qf[2];
  #pragma unroll
  for (int ks = 0; ks < 2; ks++)
    qf[ks] = *(const bf16x8*)&Qp[(size_t)i*DH + ks*32 + lg*8];

  // S^T = K * Q^T
  f32x4 sL[8], sG[2];
  #pragma unroll
  for (int f = 0; f < 8; f++){ f32x4 z = {0.f,0.f,0.f,0.f}; sL[f] = z; }
  #pragma unroll
  for (int f = 0; f < 2; f++){ f32x4 z = {0.f,0.f,0.f,0.f}; sG[f] = z; }
  #pragma unroll
  for (int f = 0; f < 8; f++){
    const short* kr = Kp + (long long)(kwin0 + f*16 + ln) * DH;   // may be <0: masked later
    #pragma unroll
    for (int ks = 0; ks < 2; ks++){
      bf16x8 kf = *(const bf16x8*)&kr[ks*32 + lg*8];
      sL[f] = __builtin_amdgcn_mfma_f32_16x16x32_bf16(kf, qf[ks], sL[f], 0, 0, 0);
    }
  }
  #pragma unroll
  for (int fg = 0; fg < 2; fg++){
    const short* kr = Kp + (size_t)(fg*16 + ln) * (WINDOW * DH);  // strided global keys
    #pragma unroll
    for (int ks = 0; ks < 2; ks++){
      bf16x8 kf = *(const bf16x8*)&kr[ks*32 + lg*8];
      sG[fg] = __builtin_amdgcn_mfma_f32_16x16x32_bf16(kf, qf[ks], sG[fg], 0, 0, 0);
    }
  }

  // ---- local softmax (over 128 keys; per lane holds 32, reduce via xor 16/32) ----
  float mx = -1e30f;
  #pragma unroll
  for (int f = 0; f < 8; f++){
    #pragma unroll
    for (int r = 0; r < 4; r++){
      int j = kwin0 + 16*f + lg*4 + r;
      bool valid = (j >= 0) && (j <= i) && (i - j <= WINDOW);
      float s = valid ? sL[f][r] * 0.125f : -1e30f;
      sL[f][r] = s;
      mx = fmaxf(mx, s);
    }
  }
  mx = fmaxf(mx, __shfl_xor(mx, 16));
  mx = fmaxf(mx, __shfl_xor(mx, 32));
  float sum = 0.f;
  #pragma unroll
  for (int f = 0; f < 8; f++){
    #pragma unroll
    for (int r = 0; r < 4; r++){
      float p = __expf(sL[f][r] - mx);
      sL[f][r] = p;
      sum += p;
    }
  }
  sum += __shfl_xor(sum, 16);
  sum += __shfl_xor(sum, 32);
  float inv = 1.f / sum;
  #pragma unroll
  for (int f = 0; f < 8; f++){
    short4v pk;
    #pragma unroll
    for (int r = 0; r < 4; r++) pk[r] = (short)f2b(sL[f][r] * inv);
    *(short4v*)&Ps[w][ln][16*f + 4*lg] = pk;
  }
  // ---- global softmax (32 keys, unmasked) ----
  float mg = -1e30f;
  #pragma unroll
  for (int fg = 0; fg < 2; fg++)
    #pragma unroll
    for (int r = 0; r < 4; r++){
      float s = sG[fg][r] * 0.125f;
      sG[fg][r] = s;
      mg = fmaxf(mg, s);
    }
  mg = fmaxf(mg, __shfl_xor(mg, 16));
  mg = fmaxf(mg, __shfl_xor(mg, 32));
  float sg2 = 0.f;
  #pragma unroll
  for (int fg = 0; fg < 2; fg++)
    #pragma unroll
    for (int r = 0; r < 4; r++){
      float p = __expf(sG[fg][r] - mg);
      sG[fg][r] = p;
      sg2 += p;
    }
  sg2 += __shfl_xor(sg2, 16);
  sg2 += __shfl_xor(sg2, 32);
  float invg = 1.f / sg2;
  #pragma unroll
  for (int fg = 0; fg < 2; fg++){
    short4v pk;
    #pragma unroll
    for (int r = 0; r < 4; r++) pk[r] = (short)f2b(sG[fg][r] * invg);
    *(short4v*)&Ps[w][ln][128 + 16*fg + 4*lg] = pk;
  }
  __syncthreads();

  // ---- PV: O[16q x 64d] = P[16 x 160] * Vcat[160 x 64] ----
  bf16x8 pa[5];
  #pragma unroll
  for (int ks = 0; ks < 5; ks++)
    pa[ks] = *(const bf16x8*)&Ps[w][ln][ks*32 + lg*8];
  f32x4 o[4];
  #pragma unroll
  for (int n16 = 0; n16 < 4; n16++){ f32x4 z = {0.f,0.f,0.f,0.f}; o[n16] = z; }
  #pragma unroll
  for (int n16 = 0; n16 < 4; n16++){
    int d = n16*16 + ln;
    #pragma unroll
    for (int ks = 0; ks < 4; ks++){
      bf16x8 vv = *(const bf16x8*)&Vt[(long long)d*N_SEQ + kwin0 + ks*32 + lg*8];
      o[n16] = __builtin_amdgcn_mfma_f32_16x16x32_bf16(pa[ks], vv, o[n16], 0, 0, 0);
    }
    bf16x8 vv = *(const bf16x8*)&Vg[d*32 + lg*8];
    o[n16] = __builtin_amdgcn_mfma_f32_16x16x32_bf16(pa[4], vv, o[n16], 0, 0, 0);
  }

  // ---- write O as bf16 into A2 [4096][KP] cols h*64+d ----
  const int h = bh & 7, b = bh >> 3;
  #pragma unroll
  for (int n16 = 0; n16 < 4; n16++){
    int d = n16*16 + ln;
    #pragma unroll
    for (int r = 0; r < 4; r++){
      int qrow = qbase + 16*w + lg*4 + r;
      A2[(size_t)(b*N_SEQ + qrow)*KP + h*DH + d] = (short)f2b(o[n16][r]);
    }
  }
}

extern "C" void kernel_launch(void* const* d_in, const int* in_sizes, int n_in,
                              void* d_out, int out_size, void* d_ws, size_t ws_size,
                              hipStream_t stream){
  const float* x      = (const float*)d_in[0];
  const float* w_qkv  = (const float*)d_in[1];
  const float* lA_qkv = (const float*)d_in[2];
  const float* lB_qkv = (const float*)d_in[3];
  const float* w_out  = (const float*)d_in[4];
  const float* b_out  = (const float*)d_in[5];
  const float* lA_out = (const float*)d_in[6];
  const float* lB_out = (const float*)d_in[7];
  float* out = (float*)d_out;

  short* A1  = (short*)d_ws;                   // [4096][KP]
  short* wT1 = A1  + (size_t)4096*KP;          // [1536][KP]
  short* wT2 = wT1 + (size_t)1536*KP;          // [512][KP]
  short* qb  = wT2 + (size_t)512*KP;           // [16][2048][64]
  short* kb  = qb  + (size_t)16*2048*64;
  short* vT  = kb  + (size_t)16*2048*64;       // [16][64][2048]
  short* vgT = vT  + (size_t)16*2048*64;       // [16][64][32]
  short* A2  = vgT + (size_t)16*64*32;         // [4096][KP]

  cvt_x<<<2048, 256, 0, stream>>>(x, A1);
  rank8_k<false><<<1024, 256, 0, stream>>>(x, lA_qkv, A1);
  build_wT<1536><<<dim3(24, 9), 256, 0, stream>>>(w_qkv, lB_qkv, 0.25f, wT1);
  build_wT<512><<<dim3(8, 9), 256, 0, stream>>>(w_out, lB_out, 0.25f, wT2);
  gemm_mfma<128,128,4,4,0><<<dim3(12, 32), 256, 0, stream>>>(A1, wT1, qb, kb, vT, vgT, nullptr, nullptr);
  attn_mfma<<<dim3(32, 16), 256, 0, stream>>>(qb, kb, vT, vgT, A2);
  rank8_k<true><<<1024, 256, 0, stream>>>(A2, lA_out, A2);
  gemm_mfma<64,128,2,4,1><<<dim3(4, 64), 256, 0, stream>>>(A2, wT2, nullptr, nullptr, nullptr, nullptr, b_out, out);
}

// Round 3
// 64.051 us; speedup vs baseline: 4.1948x; 1.1434x over previous
//
#include <hip/hip_runtime.h>

#define N_SEQ 2048
#define CDIM 512
#define HEADS 8
#define DH 64
#define WINDOW 64
#define BATCH 2
#define KP 544           // qkv GEMM K: 512 + 8 lora + 24 zero pad

typedef __attribute__((ext_vector_type(8))) short bf16x8;
typedef __attribute__((ext_vector_type(4))) short short4v;
typedef __attribute__((ext_vector_type(8))) short short8v;
typedef __attribute__((ext_vector_type(4))) float f32x4;

// ---------- helpers ----------
__device__ __forceinline__ unsigned short f2b(float f){
  unsigned u = __float_as_uint(f);
  unsigned r = (u + 0x7fffu + ((u >> 16) & 1u)) >> 16;
  return (unsigned short)r;
}
__device__ __forceinline__ float b2f(unsigned short h){ return __uint_as_float(((unsigned)h) << 16); }

__device__ __forceinline__ void gl_lds16(const void* g, void* l){
  __builtin_amdgcn_global_load_lds(
      (const __attribute__((address_space(1))) void*)g,
      (__attribute__((address_space(3))) void*)l, 16, 0, 0);
}

// ================= prep: all input conversions in ONE launch =================
// blocks [0,1024): x -> A1 bf16 cols 0..511 + rank8 lora cols 512..543
// blocks [1024,1216): w_qkv transpose tiles -> wT1
// blocks [1216,1240): wT1 lora cols 512..543
// blocks [1240,1304): w_out transpose tiles -> wT2 (stride 512)
// blocks [1304,1306): lBo[n][r] = 0.25*lB_out[r][n] bf16
// block 1306: lAT[r][k] = lA_out[k][r] bf16 (16 rows, 8 real)
__global__ __launch_bounds__(256) void prep(
    const float* __restrict__ x, const float* __restrict__ lA_qkv,
    const float* __restrict__ w_qkv, const float* __restrict__ lB_qkv,
    const float* __restrict__ w_out, const float* __restrict__ lB_out,
    const float* __restrict__ lA_out,
    short* __restrict__ A1, short* __restrict__ wT1,
    short* __restrict__ wT2, short* __restrict__ lBo, short* __restrict__ lAT){
  __shared__ float T[64][65];
  const int bx = blockIdx.x, tid = threadIdx.x;
  if (bx < 1024){
    const int w = tid >> 6, lane = tid & 63;
    const int m = bx*4 + w;
    const float4* row = (const float4*)(x + (size_t)m*CDIM);
    float acc[8] = {0.f,0.f,0.f,0.f,0.f,0.f,0.f,0.f};
    #pragma unroll
    for (int hh = 0; hh < 2; hh++){
      float4 v = row[hh*64 + lane];
      int c = hh*256 + lane*4;
      short4v pk;
      pk[0] = (short)f2b(v.x); pk[1] = (short)f2b(v.y);
      pk[2] = (short)f2b(v.z); pk[3] = (short)f2b(v.w);
      *(short4v*)&A1[(size_t)m*KP + c] = pk;
      float e[4] = {v.x, v.y, v.z, v.w};
      #pragma unroll
      for (int q = 0; q < 4; q++){
        const float* ar = lA_qkv + (size_t)(c + q)*8;
        #pragma unroll
        for (int r = 0; r < 8; r++) acc[r] += e[q]*ar[r];
      }
    }
    #pragma unroll
    for (int r = 0; r < 8; r++){
      #pragma unroll
      for (int off = 32; off; off >>= 1) acc[r] += __shfl_xor(acc[r], off);
    }
    float myv = 0.f;
    #pragma unroll
    for (int r = 0; r < 8; r++) if (lane == r) myv = acc[r];
    if (lane < 32) A1[(size_t)m*KP + 512 + lane] = (lane < 8) ? (short)f2b(myv) : (short)0;
    return;
  }
  if (bx < 1216 || (bx >= 1240 && bx < 1304)){
    const float* wsrc; short* dst; int NN, STR, ct, kt;
    if (bx < 1216){ int bxx = bx - 1024; wsrc = w_qkv; dst = wT1; NN = 1536; STR = KP;  ct = bxx % 24; kt = bxx / 24; }
    else          { int bxx = bx - 1240; wsrc = w_out; dst = wT2; NN = 512;  STR = 512; ct = bxx % 8;  kt = bxx / 8; }
    const int n0 = ct*64, k0 = kt*64;
    #pragma unroll
    for (int it = 0; it < 16; it++){
      int r = (tid >> 6) + it*4, c = tid & 63;
      T[r][c] = wsrc[(size_t)(k0 + r)*NN + n0 + c];
    }
    __syncthreads();
    #pragma unroll
    for (int it = 0; it < 16; it++){
      int rw = (tid >> 6) + it*4, cw = tid & 63;
      dst[(size_t)(n0 + rw)*STR + k0 + cw] = (short)f2b(T[cw][rw]);
    }
    return;
  }
  if (bx < 1240){
    const int n = (bx - 1216)*64 + (tid & 63);
    const int quarter = tid >> 6;
    short8v pk;
    #pragma unroll
    for (int i = 0; i < 8; i++){
      int j = quarter*8 + i;
      pk[i] = (j < 8) ? (short)f2b(0.25f * lB_qkv[(size_t)j*1536 + n]) : (short)0;
    }
    *(short8v*)&wT1[(size_t)n*KP + 512 + quarter*8] = pk;
    return;
  }
  if (bx < 1306){
    int n = (bx - 1304)*256 + tid;
    short8v pk;
    #pragma unroll
    for (int r = 0; r < 8; r++) pk[r] = (short)f2b(0.25f * lB_out[(size_t)r*512 + n]);
    *(short8v*)&lBo[(size_t)n*8] = pk;
    return;
  }
  for (int t = tid; t < 16*512; t += 256){
    int r = t >> 9, k = t & 511;
    lAT[t] = (r < 8) ? (short)f2b(lA_out[(size_t)k*8 + r]) : (short)0;
  }
}

// ================= qkv GEMM (MFMA, K=544, lora folded) + q/k/vT scatter =================
__global__ __launch_bounds__(256) void gemm_qkv(const short* __restrict__ A,
    const short* __restrict__ Bt,
    short* __restrict__ qb, short* __restrict__ kb,
    short* __restrict__ vT, short* __restrict__ vgT){
  __shared__ __align__(16) short As[128*32];
  __shared__ __align__(16) short Bs[128*32];
  const int tid = threadIdx.x;
  const int wid = tid >> 6, lane = tid & 63;
  const int ln = lane & 15, lg = lane >> 4;
  const int phys = blockIdx.y*12 + blockIdx.x;          // 384 blocks
  const int s = (phys & 7)*48 + (phys >> 3);            // XCD swizzle (384%8==0)
  const int m0 = (s/12)*128, n0 = (s%12)*128;
  const int wr = wid >> 1, wc = wid & 1;                // FM=FN=4, NWC=2
  f32x4 acc[4][4];
  #pragma unroll
  for (int mi = 0; mi < 4; mi++)
    #pragma unroll
    for (int ni = 0; ni < 4; ni++){ f32x4 z = {0.f,0.f,0.f,0.f}; acc[mi][ni] = z; }

  for (int kt = 0; kt < KP/32; kt++){
    const int k0 = kt*32;
    if (kt) __syncthreads();
    #pragma unroll
    for (int i = 0; i < 2; i++){
      int li = i*256 + tid;
      int row = li >> 2, p = li & 3;
      int sl = p ^ ((row >> 1) & 3);
      gl_lds16(&A[(size_t)(m0 + row)*KP + k0 + sl*8], &As[(i*256 + wid*64)*8]);
    }
    #pragma unroll
    for (int i = 0; i < 2; i++){
      int li = i*256 + tid;
      int row = li >> 2, p = li & 3;
      int sl = p ^ ((row >> 1) & 3);
      gl_lds16(&Bt[(size_t)(n0 + row)*KP + k0 + sl*8], &Bs[(i*256 + wid*64)*8]);
    }
    asm volatile("s_waitcnt vmcnt(0)" ::: "memory");
    __syncthreads();
    bf16x8 af[4], bfr[4];
    #pragma unroll
    for (int mi = 0; mi < 4; mi++){
      int row = wr*64 + mi*16 + ln;
      af[mi] = *(const bf16x8*)&As[row*32 + ((lg ^ ((row >> 1) & 3)) << 3)];
    }
    #pragma unroll
    for (int ni = 0; ni < 4; ni++){
      int row = wc*64 + ni*16 + ln;
      bfr[ni] = *(const bf16x8*)&Bs[row*32 + ((lg ^ ((row >> 1) & 3)) << 3)];
    }
    #pragma unroll
    for (int mi = 0; mi < 4; mi++)
      #pragma unroll
      for (int ni = 0; ni < 4; ni++)
        acc[mi][ni] = __builtin_amdgcn_mfma_f32_16x16x32_bf16(af[mi], bfr[ni], acc[mi][ni], 0, 0, 0);
  }

  #pragma unroll
  for (int mi = 0; mi < 4; mi++){
    int mbase = m0 + wr*64 + mi*16 + lg*4;
    int b = mbase >> 11, nseq = mbase & 2047;
    #pragma unroll
    for (int ni = 0; ni < 4; ni++){
      int jg = n0 + wc*64 + ni*16 + ln;
      int sq = jg >> 9, rem = jg & 511;
      int h = rem >> 6, d = rem & 63;
      size_t bh = (size_t)(b*HEADS + h);
      f32x4 a = acc[mi][ni];
      if (sq == 2){
        short4v pk;
        pk[0] = (short)f2b(a[0]); pk[1] = (short)f2b(a[1]);
        pk[2] = (short)f2b(a[2]); pk[3] = (short)f2b(a[3]);
        *(short4v*)&vT[bh*131072 + (size_t)d*2048 + nseq] = pk;
        if ((nseq & 63) == 0) vgT[bh*2048 + d*32 + (nseq >> 6)] = pk[0];
      } else {
        short* dst = (sq == 0 ? qb : kb) + bh*131072 + (size_t)nseq*64 + d;
        dst[0]   = (short)f2b(a[0]);
        dst[64]  = (short)f2b(a[1]);
        dst[128] = (short)f2b(a[2]);
        dst[192] = (short)f2b(a[3]);
      }
    }
  }
}

// ================= fused attention (MFMA) =================
__global__ __launch_bounds__(256) void attn_mfma(const short* __restrict__ qb,
    const short* __restrict__ kb, const short* __restrict__ vT,
    const short* __restrict__ vgT, short* __restrict__ A2){
  __shared__ __align__(16) short Ps[4][16][168];
  const int phys = blockIdx.y*32 + blockIdx.x;          // 512 blocks
  const int s = (phys & 7)*64 + (phys >> 3);            // XCD swizzle
  const int qt = s & 31, bh = s >> 5;
  const int qbase = qt * 64;
  const int tid = threadIdx.x, w = tid >> 6, lane = tid & 63;
  const int ln = lane & 15, lg = lane >> 4;
  const size_t base = (size_t)bh * (N_SEQ * DH);
  const short* Qp = qb + base;
  const short* Kp = kb + base;
  const short* Vt = vT + base;
  const short* Vg = vgT + (size_t)bh * (DH * 32);
  const int i = qbase + w*16 + ln;
  const int kwin0 = qbase - 64;

  bf16x8 qf[2];
  #pragma unroll
  for (int ks = 0; ks < 2; ks++)
    qf[ks] = *(const bf16x8*)&Qp[(size_t)i*DH + ks*32 + lg*8];

  f32x4 sL[8], sG[2];
  #pragma unroll
  for (int f = 0; f < 8; f++){ f32x4 z = {0.f,0.f,0.f,0.f}; sL[f] = z; }
  #pragma unroll
  for (int f = 0; f < 2; f++){ f32x4 z = {0.f,0.f,0.f,0.f}; sG[f] = z; }
  #pragma unroll
  for (int f = 0; f < 8; f++){
    const short* kr = Kp + (long long)(kwin0 + f*16 + ln) * DH;
    #pragma unroll
    for (int ks = 0; ks < 2; ks++){
      bf16x8 kf = *(const bf16x8*)&kr[ks*32 + lg*8];
      sL[f] = __builtin_amdgcn_mfma_f32_16x16x32_bf16(kf, qf[ks], sL[f], 0, 0, 0);
    }
  }
  #pragma unroll
  for (int fg = 0; fg < 2; fg++){
    const short* kr = Kp + (size_t)(fg*16 + ln) * (WINDOW * DH);
    #pragma unroll
    for (int ks = 0; ks < 2; ks++){
      bf16x8 kf = *(const bf16x8*)&kr[ks*32 + lg*8];
      sG[fg] = __builtin_amdgcn_mfma_f32_16x16x32_bf16(kf, qf[ks], sG[fg], 0, 0, 0);
    }
  }

  float mx = -1e30f;
  #pragma unroll
  for (int f = 0; f < 8; f++){
    #pragma unroll
    for (int r = 0; r < 4; r++){
      int j = kwin0 + 16*f + lg*4 + r;
      bool valid = (j >= 0) && (j <= i) && (i - j <= WINDOW);
      float sv = valid ? sL[f][r] * 0.125f : -1e30f;
      sL[f][r] = sv;
      mx = fmaxf(mx, sv);
    }
  }
  mx = fmaxf(mx, __shfl_xor(mx, 16));
  mx = fmaxf(mx, __shfl_xor(mx, 32));
  float sum = 0.f;
  #pragma unroll
  for (int f = 0; f < 8; f++){
    #pragma unroll
    for (int r = 0; r < 4; r++){
      float p = __expf(sL[f][r] - mx);
      sL[f][r] = p;
      sum += p;
    }
  }
  sum += __shfl_xor(sum, 16);
  sum += __shfl_xor(sum, 32);
  float inv = 1.f / sum;
  #pragma unroll
  for (int f = 0; f < 8; f++){
    short4v pk;
    #pragma unroll
    for (int r = 0; r < 4; r++) pk[r] = (short)f2b(sL[f][r] * inv);
    *(short4v*)&Ps[w][ln][16*f + 4*lg] = pk;
  }
  float mg = -1e30f;
  #pragma unroll
  for (int fg = 0; fg < 2; fg++)
    #pragma unroll
    for (int r = 0; r < 4; r++){
      float sv = sG[fg][r] * 0.125f;
      sG[fg][r] = sv;
      mg = fmaxf(mg, sv);
    }
  mg = fmaxf(mg, __shfl_xor(mg, 16));
  mg = fmaxf(mg, __shfl_xor(mg, 32));
  float sg2 = 0.f;
  #pragma unroll
  for (int fg = 0; fg < 2; fg++)
    #pragma unroll
    for (int r = 0; r < 4; r++){
      float p = __expf(sG[fg][r] - mg);
      sG[fg][r] = p;
      sg2 += p;
    }
  sg2 += __shfl_xor(sg2, 16);
  sg2 += __shfl_xor(sg2, 32);
  float invg = 1.f / sg2;
  #pragma unroll
  for (int fg = 0; fg < 2; fg++){
    short4v pk;
    #pragma unroll
    for (int r = 0; r < 4; r++) pk[r] = (short)f2b(sG[fg][r] * invg);
    *(short4v*)&Ps[w][ln][128 + 16*fg + 4*lg] = pk;
  }
  __syncthreads();

  bf16x8 pa[5];
  #pragma unroll
  for (int ks = 0; ks < 5; ks++)
    pa[ks] = *(const bf16x8*)&Ps[w][ln][ks*32 + lg*8];
  f32x4 o[4];
  #pragma unroll
  for (int n16 = 0; n16 < 4; n16++){ f32x4 z = {0.f,0.f,0.f,0.f}; o[n16] = z; }
  #pragma unroll
  for (int n16 = 0; n16 < 4; n16++){
    int d = n16*16 + ln;
    #pragma unroll
    for (int ks = 0; ks < 4; ks++){
      bf16x8 vv = *(const bf16x8*)&Vt[(long long)d*N_SEQ + kwin0 + ks*32 + lg*8];
      o[n16] = __builtin_amdgcn_mfma_f32_16x16x32_bf16(pa[ks], vv, o[n16], 0, 0, 0);
    }
    bf16x8 vv = *(const bf16x8*)&Vg[d*32 + lg*8];
    o[n16] = __builtin_amdgcn_mfma_f32_16x16x32_bf16(pa[4], vv, o[n16], 0, 0, 0);
  }

  const int h = bh & 7, b = bh >> 3;
  #pragma unroll
  for (int n16 = 0; n16 < 4; n16++){
    int d = n16*16 + ln;
    #pragma unroll
    for (int r = 0; r < 4; r++){
      int qrow = qbase + 16*w + lg*4 + r;
      A2[(size_t)(b*N_SEQ + qrow)*CDIM + h*DH + d] = (short)f2b(o[n16][r]);
    }
  }
}

// ================= out GEMM (K=512) + fused rank-8 lora + bias =================
__global__ __launch_bounds__(256) void gemm_out(const short* __restrict__ A,
    const short* __restrict__ Bt, const short* __restrict__ lBo,
    const short* __restrict__ lAT, const float* __restrict__ bias,
    float* __restrict__ outp){
  __shared__ __align__(16) short As[64*32];
  __shared__ __align__(16) short Bs[128*32];
  __shared__ float aoLDS[64][8];
  const int tid = threadIdx.x;
  const int wid = tid >> 6, lane = tid & 63;
  const int ln = lane & 15, lg = lane >> 4;
  const int phys = blockIdx.y*4 + blockIdx.x;           // 256 blocks
  const int s = (phys & 7)*32 + (phys >> 3);            // XCD swizzle
  const int m0 = (s >> 2)*64, n0 = (s & 3)*128;
  const int wr = wid >> 1, wc = wid & 1;                // FM=2, FN=4, NWC=2
  f32x4 acc[2][4];
  f32x4 aoacc[2];
  #pragma unroll
  for (int mi = 0; mi < 2; mi++){
    f32x4 z = {0.f,0.f,0.f,0.f};
    aoacc[mi] = z;
    #pragma unroll
    for (int ni = 0; ni < 4; ni++) acc[mi][ni] = z;
  }

  for (int kt = 0; kt < 16; kt++){
    const int k0 = kt*32;
    if (kt) __syncthreads();
    {
      int row = tid >> 2, p = tid & 3;
      int sl = p ^ ((row >> 1) & 3);
      gl_lds16(&A[(size_t)(m0 + row)*CDIM + k0 + sl*8], &As[(wid*64)*8]);
    }
    #pragma unroll
    for (int i = 0; i < 2; i++){
      int li = i*256 + tid;
      int row = li >> 2, p = li & 3;
      int sl = p ^ ((row >> 1) & 3);
      gl_lds16(&Bt[(size_t)(n0 + row)*CDIM + k0 + sl*8], &Bs[(i*256 + wid*64)*8]);
    }
    asm volatile("s_waitcnt vmcnt(0)" ::: "memory");
    __syncthreads();
    bf16x8 af[2], bfr[4];
    #pragma unroll
    for (int mi = 0; mi < 2; mi++){
      int row = wr*32 + mi*16 + ln;
      af[mi] = *(const bf16x8*)&As[row*32 + ((lg ^ ((row >> 1) & 3)) << 3)];
    }
    #pragma unroll
    for (int ni = 0; ni < 4; ni++){
      int row = wc*64 + ni*16 + ln;
      bfr[ni] = *(const bf16x8*)&Bs[row*32 + ((lg ^ ((row >> 1) & 3)) << 3)];
    }
    bf16x8 bfl = *(const bf16x8*)&lAT[(size_t)ln*512 + k0 + lg*8];  // tiny, L1-hot
    #pragma unroll
    for (int mi = 0; mi < 2; mi++){
      aoacc[mi] = __builtin_amdgcn_mfma_f32_16x16x32_bf16(af[mi], bfl, aoacc[mi], 0, 0, 0);
      #pragma unroll
      for (int ni = 0; ni < 4; ni++)
        acc[mi][ni] = __builtin_amdgcn_mfma_f32_16x16x32_bf16(af[mi], bfr[ni], acc[mi][ni], 0, 0, 0);
    }
  }

  // distribute ao (rows x 8) via LDS
  if (wc == 0 && ln < 8){
    #pragma unroll
    for (int mi = 0; mi < 2; mi++)
      #pragma unroll
      for (int j = 0; j < 4; j++)
        aoLDS[wr*32 + mi*16 + lg*4 + j][ln] = aoacc[mi][j];
  }
  __syncthreads();

  #pragma unroll
  for (int mi = 0; mi < 2; mi++){
    #pragma unroll
    for (int j = 0; j < 4; j++){
      int rl = wr*32 + mi*16 + lg*4 + j;
      int m = m0 + rl;
      float ao8[8];
      #pragma unroll
      for (int r = 0; r < 8; r++) ao8[r] = aoLDS[rl][r];
      #pragma unroll
      for (int ni = 0; ni < 4; ni++){
        int jg = n0 + wc*64 + ni*16 + ln;
        bf16x8 lbv = *(const bf16x8*)&lBo[(size_t)jg*8];
        float lora = 0.f;
        #pragma unroll
        for (int r = 0; r < 8; r++) lora += ao8[r] * b2f((unsigned short)lbv[r]);
        outp[(size_t)m*CDIM + jg] = acc[mi][ni][j] + bias[jg] + lora;
      }
    }
  }
}

extern "C" void kernel_launch(void* const* d_in, const int* in_sizes, int n_in,
                              void* d_out, int out_size, void* d_ws, size_t ws_size,
                              hipStream_t stream){
  const float* x      = (const float*)d_in[0];
  const float* lA_qkv = (const float*)d_in[2];
  const float* lB_qkv = (const float*)d_in[3];
  const float* w_qkv  = (const float*)d_in[1];
  const float* w_out  = (const float*)d_in[4];
  const float* b_out  = (const float*)d_in[5];
  const float* lA_out = (const float*)d_in[6];
  const float* lB_out = (const float*)d_in[7];
  float* out = (float*)d_out;

  short* A1  = (short*)d_ws;                       // [4096][544]
  short* wT1 = A1  + (size_t)4096*KP;              // [1536][544]
  short* wT2 = wT1 + (size_t)1536*KP;              // [512][512]
  short* lBo = wT2 + (size_t)512*512;              // [512][8]
  short* lAT = lBo + (size_t)512*8;                // [16][512]
  short* qb  = lAT + (size_t)16*512;               // [16][2048][64]
  short* kb  = qb  + (size_t)16*2048*64;
  short* vT  = kb  + (size_t)16*2048*64;           // [16][64][2048]
  short* vgT = vT  + (size_t)16*2048*64;           // [16][64][32]
  short* A2  = vgT + (size_t)16*64*32;             // [4096][512]

  prep<<<1307, 256, 0, stream>>>(x, lA_qkv, w_qkv, lB_qkv, w_out, lB_out, lA_out,
                                 A1, wT1, wT2, lBo, lAT);
  gemm_qkv<<<dim3(12, 32), 256, 0, stream>>>(A1, wT1, qb, kb, vT, vgT);
  attn_mfma<<<dim3(32, 16), 256, 0, stream>>>(qb, kb, vT, vgT, A2);
  gemm_out<<<dim3(4, 64), 256, 0, stream>>>(A2, wT2, lBo, lAT, b_out, out);
}